// Round 8
// baseline (565.893 us; speedup 1.0000x reference)
//
#include <hip/hip_runtime.h>

// BlockEnd: out[b,a,f] = (a < M[b]) ? relu( sum_r resid[b,a,r]*w[r,f] + node[b,a,f] ) : 0
// B=4096, A=RF=F=128. fp32 in/out; compute via bf16 MFMA (16x16x32).
//
// R8: R5 (batched prologue loads) was NEUTRAL vs R4 (~150us dispatch both) ->
// per-wave drains are already hidden by TLP. Remaining gap vs the ~80us
// fabric floor (514 MB @ 6.5 TB/s, demonstrated by the harness fill kernel)
// is intra-block imbalance: block lifetime = wave0 (always active) while
// waves 1-3 are masked with p=25/50/75% -> only ~7 worker waves/CU, phase-
// bursty. Fix: decouple waves from blocks. 768 blocks (3/CU, one resident
// generation) stage wTs once; then each wave independently loops over 16384
// (molecule,strip) tasks with NO further barriers (wT read-only). Task
// decode cycles strips per wave -> balanced work, continuously-busy waves,
// desynchronized load phases. Per-task body identical to R5's measured one.

typedef __bf16 bf16x8 __attribute__((ext_vector_type(8)));
typedef float f32x4 __attribute__((ext_vector_type(4)));

static_assert(sizeof(bf16x8) == 16, "bf16x8 must be 16B");
static_assert(sizeof(f32x4) == 16, "f32x4 must be 16B");

// wTs: f-major bf16 weights, pre-swizzled so a LINEAR copy into LDS yields the
// XOR-swizzled layout: 16B unit (f, cu) holds wT_logical[f][(cu^(f&7))*8 .. +7].
__global__ __launch_bounds__(256) void wT_kernel(const float* __restrict__ w,
                                                 __bf16* __restrict__ wTs) {
    int i  = blockIdx.x * 256 + threadIdx.x;  // 0..16383 = f*128 + k
    int f  = i >> 7;
    int k  = i & 127;
    int cu = k >> 3;
    int j  = k & 7;
    int r  = ((cu ^ (f & 7)) << 3) | j;
    wTs[i] = (__bf16)w[r * 128 + f];
}

__global__ __launch_bounds__(256, 3) void blockend_kernel(
    const float* __restrict__ node,    // [B,128,128]
    const float* __restrict__ resid,   // [B,128,128]
    const __bf16* __restrict__ wTs,    // [128(f),128(r)] bf16, pre-swizzled
    const int*   __restrict__ mol,     // [B,2] int32 pairs (low word of int64)
    float*       __restrict__ out)     // [B,128,128]
{
    __shared__ __align__(16) unsigned char lds[32768];

    const int t    = threadIdx.x;
    const int wave = t >> 6;
    const int lane = t & 63;
    const int quad = lane >> 4;
    const int m16  = lane & 15;

    // ---- stage pre-swizzled weights -> LDS once: linear dest, conflict-free ----
#pragma unroll
    for (int i = 0; i < 8; ++i) {
        bf16x8 v = *(const bf16x8*)(wTs + (i * 256 + t) * 8);
        *(bf16x8*)(lds + i * 4096 + t * 16) = v;
    }
    __syncthreads();   // the ONLY barrier; wT is read-only afterwards

    // ---- swizzled LDS read addresses (loop-invariant) ----
    const int xr = m16 & 7;
    int raddr[4];
#pragma unroll
    for (int kk = 0; kk < 4; ++kk)
        raddr[kk] = m16 * 256 + ((((kk << 2) | quad) ^ xr) << 4);

    // ---- per-wave task loop over 16384 (molecule, strip) tasks ----
    const int wid    = blockIdx.x * 4 + wave;   // 0..3071
    const int NWAVES = 768 * 4;                 // 3072

    for (int tau = wid; tau < 16384; tau += NWAVES) {
        const int b      = tau >> 2;
        const int strip  = ((tau & 3) + (b >> 8)) & 3;  // cycles strips per wave
        const int M      = mol[2 * b];                  // wave-uniform -> s_load
        const int a_base = strip * 32;
        const size_t base = (size_t)b * (128 * 128);
        float* outW = out + base + (size_t)a_base * 128;

        if (M <= a_base) {
            // masked strip: 32 rows x 128 cols of zeros, coalesced float4
            f32x4 z = {0.f, 0.f, 0.f, 0.f};
            f32x4* p = (f32x4*)outW;
#pragma unroll
            for (int it = 0; it < 16; ++it)
                p[it * 64 + lane] = z;
            continue;
        }

        // Inactive lanes clamp their load row to strip row 0 (valid: a_base < M
        // here) -> duplicate reads are L1 hits, ~0 extra HBM.
        const bool act0 = (a_base + m16) < M;
        const bool act1 = (a_base + 16 + m16) < M;
        const int  rr0  = act0 ? m16        : 0;
        const int  rr1  = act1 ? (16 + m16) : 0;

        const float* rowR0 = resid + base + (size_t)(a_base + rr0) * 128;
        const float* rowR1 = resid + base + (size_t)(a_base + rr1) * 128;
        const float* rowN0 = node  + base + (size_t)(a_base + rr0) * 128;
        const float* rowN1 = node  + base + (size_t)(a_base + rr1) * 128;

        // ALL 32 data loads in one batch (R5's measured arrangement).
        f32x4 rl[2][4], rh[2][4], nd[2][8];
#pragma unroll
        for (int kk = 0; kk < 4; ++kk) {
            rl[0][kk] = *(const f32x4*)(rowR0 + kk * 32 + quad * 8);
            rh[0][kk] = *(const f32x4*)(rowR0 + kk * 32 + quad * 8 + 4);
            rl[1][kk] = *(const f32x4*)(rowR1 + kk * 32 + quad * 8);
            rh[1][kk] = *(const f32x4*)(rowR1 + kk * 32 + quad * 8 + 4);
        }
#pragma unroll
        for (int ft = 0; ft < 8; ++ft) {
            nd[0][ft] = *(const f32x4*)(rowN0 + ft * 16 + quad * 4);
            nd[1][ft] = *(const f32x4*)(rowN1 + ft * 16 + quad * 4);
        }
#pragma unroll
        for (int kk = 0; kk < 4; ++kk)
            asm volatile("" : "+v"(rl[0][kk]), "+v"(rh[0][kk]),
                              "+v"(rl[1][kk]), "+v"(rh[1][kk]));
#pragma unroll
        for (int ft = 0; ft < 8; ++ft)
            asm volatile("" : "+v"(nd[0][ft]), "+v"(nd[1][ft]));

        // ---- f32 -> bf16 B-operand fragments ----
        bf16x8 rfrag[2][4];
#pragma unroll
        for (int nt = 0; nt < 2; ++nt)
#pragma unroll
            for (int kk = 0; kk < 4; ++kk) {
                bf16x8 v;
                v[0] = (__bf16)rl[nt][kk][0]; v[1] = (__bf16)rl[nt][kk][1];
                v[2] = (__bf16)rl[nt][kk][2]; v[3] = (__bf16)rl[nt][kk][3];
                v[4] = (__bf16)rh[nt][kk][0]; v[5] = (__bf16)rh[nt][kk][1];
                v[6] = (__bf16)rh[nt][kk][2]; v[7] = (__bf16)rh[nt][kk][3];
                rfrag[nt][kk] = v;
            }

        f32x4 acc[2][8];
#pragma unroll
        for (int nt = 0; nt < 2; ++nt)
#pragma unroll
            for (int ft = 0; ft < 8; ++ft)
                acc[nt][ft] = (f32x4){0.f, 0.f, 0.f, 0.f};

        // ---- MFMA loop: wfrag from LDS, reused across both nt sub-tiles ----
#pragma unroll
        for (int ft = 0; ft < 8; ++ft) {
#pragma unroll
            for (int kk = 0; kk < 4; ++kk) {
                bf16x8 wfrag = *(const bf16x8*)(lds + ft * 4096 + raddr[kk]);
                acc[0][ft] = __builtin_amdgcn_mfma_f32_16x16x32_bf16(
                    wfrag, rfrag[0][kk], acc[0][ft], 0, 0, 0);
                acc[1][ft] = __builtin_amdgcn_mfma_f32_16x16x32_bf16(
                    wfrag, rfrag[1][kk], acc[1][ft], 0, 0, 0);
            }
        }

        // ---- epilogue: pure VALU + stores ----
        // C layout (A=wT so m->f): f = ft*16 + quad*4 + reg, a = m16 (+ nt*16).
#pragma unroll
        for (int ft = 0; ft < 8; ++ft) {
            const int off = m16 * 128 + ft * 16 + quad * 4;
            f32x4 v;
#pragma unroll
            for (int i = 0; i < 4; ++i) {
                float x = acc[0][ft][i] + nd[0][ft][i];
                v[i] = (act0 && x > 0.f) ? x : 0.f;
            }
            *(f32x4*)(outW + off) = v;
        }
#pragma unroll
        for (int ft = 0; ft < 8; ++ft) {
            const int off = (16 + m16) * 128 + ft * 16 + quad * 4;
            f32x4 v;
#pragma unroll
            for (int i = 0; i < 4; ++i) {
                float x = acc[1][ft][i] + nd[1][ft][i];
                v[i] = (act1 && x > 0.f) ? x : 0.f;
            }
            *(f32x4*)(outW + off) = v;
        }
    }
}

extern "C" void kernel_launch(void* const* d_in, const int* in_sizes, int n_in,
                              void* d_out, int out_size, void* d_ws, size_t ws_size,
                              hipStream_t stream) {
    const float* node  = (const float*)d_in[0];   // node_features    [4096,128,128]
    const float* resid = (const float*)d_in[1];   // residual_features[4096,128,128]
    const float* w     = (const float*)d_in[2];   // w [128,128]
    const int*   mol   = (const int*)d_in[3];     // mol_slice [4096,2] int64 -> int32 pairs
    float*       out   = (float*)d_out;
    __bf16*      wTs   = (__bf16*)d_ws;           // 32 KB scratch (pre-swizzled)

    wT_kernel<<<64, 256, 0, stream>>>(w, wTs);
    blockend_kernel<<<768, 256, 0, stream>>>(node, resid, wTs, mol, out);
}

// Round 12
// 560.184 us; speedup vs baseline: 1.0102x; 1.0102x over previous
//
#include <hip/hip_runtime.h>

// BlockEnd: out[b,a,f] = (a < M[b]) ? relu( sum_r resid[b,a,r]*w[r,f] + node[b,a,f] ) : 0
// B=4096, A=RF=F=128. fp32 in/out; compute via bf16 MFMA (16x16x32).
//
// R9 (resubmitted; broker timeouts R10-R12): every register-scheduling variant
// pinned at ~2.6-2.9 TB/s because reads are outstanding only during each
// wave's short load phase (~9KB/CU avg vs the ~23KB Little's-law needs).
// Fix: hold in-flight reads in LDS, not VGPRs.
// Persistent kernel, 256 blocks x 192 thr (3 waves), 128KB dynamic LDS:
//   [0,32K)   wT, pre-swizzled bf16 (proven R4 layout, shared)
//   +32K      3 waves x 2 x 16KB private slots (resid 8K + node 8K, 16-row task)
// Per wave task loop (NO barriers): issue 16 global_load_lds for next task ->
// s_waitcnt vmcnt(24) (retires previous DMA only; current 16 + 8 stores stay
// outstanding) -> compute current task from LDS -> 8 stores. In-order vmcnt
// retirement makes counted waits safe vs stray VMEM (only adds over-wait).
// Resid/node staged with source-side XOR swizzle (linear gll dest, rule #21).
// Masked rows: clamp DMA *source* row to M-1 (L2 dup hits, no overfetch).

typedef __bf16 bf16x8 __attribute__((ext_vector_type(8)));
typedef float f32x4 __attribute__((ext_vector_type(4)));

static_assert(sizeof(bf16x8) == 16, "bf16x8 must be 16B");
static_assert(sizeof(f32x4) == 16, "f32x4 must be 16B");

#define NT 32768            // tasks: 4096 molecules x 8 strips of 16 rows
#define NW 768              // waves: 256 blocks x 3
#define LDS_TOTAL 131072    // 32K wT + 3*2*16K slots

// wTs: f-major bf16 weights, pre-swizzled so a LINEAR copy into LDS yields the
// XOR-swizzled layout: 16B unit (f, cu) holds wT_logical[f][(cu^(f&7))*8 .. +7].
__global__ __launch_bounds__(256) void wT_kernel(const float* __restrict__ w,
                                                 __bf16* __restrict__ wTs) {
    int i  = blockIdx.x * 256 + threadIdx.x;  // 0..16383 = f*128 + k
    int f  = i >> 7;
    int k  = i & 127;
    int cu = k >> 3;
    int j  = k & 7;
    int r  = ((cu ^ (f & 7)) << 3) | j;
    wTs[i] = (__bf16)w[r * 128 + f];
}

// Stage one 16-row x 128-f32 region (8KB) into LDS via 8 global_load_lds.
// LDS dest is linear (wave-uniform base + lane*16); the XOR swizzle is applied
// to the per-lane GLOBAL source unit index, so LDS[r][c] = G[r][c ^ (r&7)].
// Source row clamped to M-1 (rows >= M are dead; dup reads hit L1/L2).
__device__ __forceinline__ void issue_dma_region(const char* gmol, char* slotRegion,
                                                 int aBase, int M, int lrow2, int lcol) {
#pragma unroll
    for (int i = 0; i < 8; ++i) {
        const int row  = 2 * i + lrow2;                     // 0..15 strip-local
        const int grow = min(aBase + row, M - 1);           // clamped global row
        const int gb   = grow * 512 + ((lcol ^ (row & 7)) << 4);
        auto src = (const __attribute__((address_space(1))) unsigned int*)(gmol + gb);
        auto dst = (__attribute__((address_space(3))) unsigned int*)(slotRegion + i * 1024);
        __builtin_amdgcn_global_load_lds(src, dst, 16, 0, 0);
    }
}

__global__ __launch_bounds__(192, 1) void blockend_kernel(
    const float* __restrict__ node,    // [B,128,128]
    const float* __restrict__ resid,   // [B,128,128]
    const __bf16* __restrict__ wTs,    // [128(f),128(r)] bf16, pre-swizzled
    const int*   __restrict__ mol,     // [B,2] int32 pairs (low word of int64)
    float*       __restrict__ out)     // [B,128,128]
{
    extern __shared__ __attribute__((aligned(16))) char smem[];

    const int t     = threadIdx.x;
    const int lane  = t & 63;
    const int quad  = lane >> 4;
    const int m16   = lane & 15;
    const int lrow2 = lane >> 5;    // row-within-pair for DMA
    const int lcol  = lane & 31;    // 16B-unit col for DMA
    const int wv    = __builtin_amdgcn_readfirstlane(t >> 6);

    // ---- stage pre-swizzled wT -> LDS [0,32768) ----
    {
        const bf16x8* srcw = (const bf16x8*)wTs;
        for (int u = t; u < 2048; u += 192)
            *(bf16x8*)(smem + u * 16) = srcw[u];
    }
    __syncthreads();   // the ONLY barrier in the kernel

    char* slot0 = smem + 32768 + wv * 32768;
    char* slot1 = slot0 + 16384;

    const int wid = blockIdx.x * 3 + wv;   // 0..767

    int tau   = wid;
    int b0    = __builtin_amdgcn_readfirstlane(tau >> 3);
    int M_cur = mol[2 * b0];
    int b1    = __builtin_amdgcn_readfirstlane((tau + NW) >> 3);
    int M_next = mol[2 * b1];

    // ---- prime slot0 with task tau ----
    {
        const char* rm = (const char*)resid + (size_t)b0 * 65536;
        const char* nm = (const char*)node  + (size_t)b0 * 65536;
        const int aB = (tau & 7) * 16;
        issue_dma_region(rm, slot0,        aB, M_cur, lrow2, lcol);
        issue_dma_region(nm, slot0 + 8192, aB, M_cur, lrow2, lcol);
    }

    int p = 0;
    bool first = true;

    for (; tau < NT; tau += NW) {
        // ---- issue DMA for next task into the other slot (16 gll) ----
        {
            const int tn = min(tau + NW, NT - 1);   // last iter: harmless dummy re-stage
            const int bn = tn >> 3;
            const char* rm = (const char*)resid + (size_t)bn * 65536;
            const char* nm = (const char*)node  + (size_t)bn * 65536;
            char* s = p ? slot0 : slot1;
            const int aB = (tn & 7) * 16;
            issue_dma_region(rm, s,        aB, M_next, lrow2, lcol);
            issue_dma_region(nm, s + 8192, aB, M_next, lrow2, lcol);
        }
        // prefetch M two tasks ahead (uniform -> s_load, lgkm not vmcnt)
        const int bn2 = __builtin_amdgcn_readfirstlane(min(tau + 2 * NW, NT - 1) >> 3);
        const int M_next2 = mol[2 * bn2];

        __builtin_amdgcn_sched_barrier(0);
        // Counted wait: retire only the PREVIOUS task's 16 DMA ops (oldest).
        // Queue at this point (old->new): prevDMA 16 | prev stores 8 | nextDMA 16.
        // vmcnt(24) retires exactly prevDMA; mask-independent (masked tasks also
        // issue 8 stores). First iter: prime 16 + next 16 -> vmcnt(16).
        if (first) { asm volatile("s_waitcnt vmcnt(16)" ::: "memory"); first = false; }
        else       { asm volatile("s_waitcnt vmcnt(24)" ::: "memory"); }
        __builtin_amdgcn_sched_barrier(0);

        // ---- compute task tau from slot p (pure LDS/VALU/MFMA + 8 stores) ----
        {
            const int b     = tau >> 3;
            const int aBase = (tau & 7) * 16;
            float* outW = out + (size_t)b * 16384 + (size_t)aBase * 128;
            const char* S = p ? slot1 : slot0;

            if (aBase < M_cur) {
                const int x = m16 & 7;
                // rfrag[kk] = resid[a=aBase+m16][k=kk*32+quad*8 ..+7] -> bf16
                bf16x8 rfrag[4];
#pragma unroll
                for (int kk = 0; kk < 4; ++kk) {
                    const int u0 = kk * 8 + quad * 2;
                    f32x4 lo = *(const f32x4*)(S + m16 * 512 + (((u0    ) ^ x) << 4));
                    f32x4 hi = *(const f32x4*)(S + m16 * 512 + (((u0 + 1) ^ x) << 4));
                    bf16x8 v;
                    v[0] = (__bf16)lo[0]; v[1] = (__bf16)lo[1];
                    v[2] = (__bf16)lo[2]; v[3] = (__bf16)lo[3];
                    v[4] = (__bf16)hi[0]; v[5] = (__bf16)hi[1];
                    v[6] = (__bf16)hi[2]; v[7] = (__bf16)hi[3];
                    rfrag[kk] = v;
                }
                f32x4 acc[8];
#pragma unroll
                for (int ft = 0; ft < 8; ++ft) acc[ft] = (f32x4){0.f, 0.f, 0.f, 0.f};
#pragma unroll
                for (int ft = 0; ft < 8; ++ft)
#pragma unroll
                    for (int kk = 0; kk < 4; ++kk) {
                        bf16x8 wfrag = *(const bf16x8*)(smem + ft * 4096 + m16 * 256
                                            + ((((kk << 2) | quad) ^ x) << 4));
                        acc[ft] = __builtin_amdgcn_mfma_f32_16x16x32_bf16(
                            wfrag, rfrag[kk], acc[ft], 0, 0, 0);
                    }
                // epilogue: node from LDS; C layout (A=wT so m->f):
                // f = ft*16 + quad*4 + reg, a = m16.
                const bool act = (aBase + m16) < M_cur;
#pragma unroll
                for (int ft = 0; ft < 8; ++ft) {
                    const int un = ft * 4 + quad;
                    f32x4 nd = *(const f32x4*)(S + 8192 + m16 * 512 + ((un ^ x) << 4));
                    f32x4 v;
#pragma unroll
                    for (int i = 0; i < 4; ++i) {
                        float xx = acc[ft][i] + nd[i];
                        v[i] = (act && xx > 0.f) ? xx : 0.f;
                    }
                    *(f32x4*)(outW + m16 * 128 + ft * 16 + quad * 4) = v;
                }
            } else {
                // masked strip: 16 rows x 128 cols of zeros (8 stores, same count)
                f32x4 z = {0.f, 0.f, 0.f, 0.f};
                f32x4* pp = (f32x4*)outW;
#pragma unroll
                for (int it = 0; it < 8; ++it)
                    pp[it * 64 + lane] = z;
            }
        }
        __builtin_amdgcn_sched_barrier(0);
        p ^= 1;
        M_cur  = M_next;
        M_next = M_next2;
    }
}

extern "C" void kernel_launch(void* const* d_in, const int* in_sizes, int n_in,
                              void* d_out, int out_size, void* d_ws, size_t ws_size,
                              hipStream_t stream) {
    const float* node  = (const float*)d_in[0];   // node_features    [4096,128,128]
    const float* resid = (const float*)d_in[1];   // residual_features[4096,128,128]
    const float* w     = (const float*)d_in[2];   // w [128,128]
    const int*   mol   = (const int*)d_in[3];     // mol_slice [4096,2] int64 -> int32 pairs
    float*       out   = (float*)d_out;
    __bf16*      wTs   = (__bf16*)d_ws;           // 32 KB scratch (pre-swizzled)

    static bool attr_set = false;
    if (!attr_set) {
        hipFuncSetAttribute(reinterpret_cast<const void*>(blockend_kernel),
                            hipFuncAttributeMaxDynamicSharedMemorySize, LDS_TOTAL);
        attr_set = true;
    }

    wT_kernel<<<64, 256, 0, stream>>>(w, wTs);
    blockend_kernel<<<256, 192, LDS_TOTAL, stream>>>(node, resid, wTs, mol, out);
}